// Round 4
// baseline (9992.344 us; speedup 1.0000x reference)
//
#include <hip/hip_runtime.h>
#include <cmath>

#define NPTS 4096
#define LOG2E_F 1.4426950408889634f
#define LN2_F   0.6931471805599453f
#define BLOG_F  -8.31776616671934f   /* -ln(4096) */

typedef __attribute__((ext_vector_type(8))) short s16x8;
typedef __attribute__((ext_vector_type(4))) float f32x4;

__device__ __forceinline__ ushort bf16h(float f) {
    uint u = __float_as_uint(f);
    return (ushort)((u + 0x7fffu + ((u >> 16) & 1u)) >> 16);
}
__device__ __forceinline__ float bf16tof(ushort h) {
    return __uint_as_float(((uint)h) << 16);
}

// norms[0][b][i] = 0.5*|x_i|^2 ; norms[1][b][i] = 0.5*|y_i|^2
__global__ __launch_bounds__(256) void norms_kernel(const float* __restrict__ x,
                                                    const float* __restrict__ y,
                                                    float* __restrict__ norms) {
    int flat = blockIdx.x * 256 + threadIdx.x;   // 0..32767
    int which = flat >> 14;
    int rem = flat & 16383;
    int b = rem >> 12;
    int i = rem & 4095;
    const float* p = (which ? y : x) + (size_t)b * 64 * NPTS + i;
    float s = 0.f;
#pragma unroll
    for (int c = 0; c < 64; ++c) {
        float v = p[(size_t)c * NPTS];
        s += v * v;
    }
    norms[flat] = 0.5f * s;
}

// Split prepass, "staging-order" layout:
//   split[(which*4+b)][tile128 = n>>7][chunk][8 ushorts]
//   chunk = g*128 + p, p = n&127; g 0..7 = hi comp-octet (comps g*8..g*8+7),
//   g 8..15 = lo octets. Per j-tile the hi half is a contiguous 16 KB run.
// One thread per (which,b,g,point-octet): fully coalesced reads and writes.
__global__ __launch_bounds__(256) void split_kernel(const float* __restrict__ x,
                                                    const float* __restrict__ y,
                                                    ushort* __restrict__ split) {
    int flat = blockIdx.x * 256 + threadIdx.x;   // 0..262143
    int n = flat & 4095;
    int g = (flat >> 12) & 7;
    int b = (flat >> 15) & 3;
    int which = flat >> 17;
    const float* src = (which ? y : x) + (size_t)b * 64 * NPTS + (size_t)g * 8 * NPTS + n;
    size_t base = ((size_t)(which * 4 + b) * 32 + (n >> 7)) * 2048 + (n & 127);
    ushort hh[8], ll[8];
#pragma unroll
    for (int e = 0; e < 8; ++e) {
        float v = src[(size_t)e * NPTS];
        hh[e] = bf16h(v);
        ll[e] = bf16h(v - bf16tof(hh[e]));
    }
    uint4 hw, lw;
    hw.x = (uint)hh[0] | ((uint)hh[1] << 16);
    hw.y = (uint)hh[2] | ((uint)hh[3] << 16);
    hw.z = (uint)hh[4] | ((uint)hh[5] << 16);
    hw.w = (uint)hh[6] | ((uint)hh[7] << 16);
    lw.x = (uint)ll[0] | ((uint)ll[1] << 16);
    lw.y = (uint)ll[2] | ((uint)ll[3] << 16);
    lw.z = (uint)ll[4] | ((uint)ll[5] << 16);
    lw.w = (uint)ll[6] | ((uint)ll[7] << 16);
    *(uint4*)&split[(base + (size_t)g * 128) * 8]       = hw;
    *(uint4*)&split[(base + (size_t)(g + 8) * 128) * 8] = lw;
}

// One annealing phase. 16x16x32 bf16 MFMA, 2-pass split (ah*bh + al*bh).
// acc init = C-bias (eps*blog + g_j - yn_j); s_nat = acc/eps.
// mat 0: f_ba rows=x cols=y (h prev[1]); 1: g_ab rows=y cols=x (prev[0])
// mat 2: f_aa rows=x cols=x (prev[2]);   3: g_bb rows=y cols=y (prev[3])
__global__ __launch_bounds__(256, 4) void softmin_kernel(
    const ushort* __restrict__ split, const float* __restrict__ norms,
    const float* __restrict__ prev, float* __restrict__ next,
    float eps, int use_prev, int do_avg)
{
    __shared__ __align__(16) ushort Bt[8192];   // 16 KB: [g 0..7][p 0..127][8]

    const int tid   = threadIdx.x;
    const int bid   = blockIdx.x;
    const int b     = bid & 3;           // round-robin XCDs -> one batch per XCD
    const int mat   = (bid >> 2) & 3;
    const int itile = bid >> 4;          // 0..63 (64-row tiles)

    const int row_is_x = (mat == 0 || mat == 2);
    const int col_is_x = (mat == 1 || mat == 2);
    const ushort* rowsplit = split + (size_t)((row_is_x ? 0 : 4) + b) * 32 * 2048 * 8;
    const ushort* colsplit = split + (size_t)((col_is_x ? 0 : 4) + b) * 32 * 2048 * 8;
    const float* rownorm = norms + (row_is_x ? 0 : 16384) + b * NPTS;
    const float* colnorm = norms + (col_is_x ? 0 : 16384) + b * NPTS;
    const int hmat = (mat == 0) ? 1 : ((mat == 1) ? 0 : mat);
    const float* hvec   = prev + (size_t)(hmat * 4 + b) * NPTS;
    const float* avgvec = prev + (size_t)(mat  * 4 + b) * NPTS;
    float*       outvec = next + (size_t)(mat  * 4 + b) * NPTS;

    const float se      = (1.0f / eps) * LOG2E_F;
    const float epsblog = eps * BLOG_F;

    const int wave = tid >> 6;
    const int lane = tid & 63;
    const int l16  = lane & 15;    // A row / B col / D col
    const int q    = lane >> 4;    // k-quad for A/B, row-quad for D
    const int i0   = itile * 64;
    const int arow = i0 + wave * 16 + l16;

    // ---- A fragments (hi + lo), once per block, from pre-split global
    // chunk for (kc,q): g = kc*4+q (hi), +8 (lo); tile = arow>>7, p = arow&127
    s16x8 ah[2], al[2];
    {
        const ushort* abase = rowsplit + ((size_t)(arow >> 7) * 2048 + (arow & 127)) * 8;
#pragma unroll
        for (int kc = 0; kc < 2; ++kc) {
            int g = kc * 4 + q;
            ah[kc] = *(const s16x8*)&abase[(size_t)g * 128 * 8];
            al[kc] = *(const s16x8*)&abase[(size_t)(g + 8) * 128 * 8];
        }
    }

    float m[4], l[4];
#pragma unroll
    for (int r = 0; r < 4; ++r) { m[r] = -__builtin_inff(); l[r] = 0.f; }

    // ---- prologue: stage tile 0 (hi half = first 16 KB of the tile block)
    uint4 pr[4];
#pragma unroll
    for (int k = 0; k < 4; ++k)
        pr[k] = *(const uint4*)&colsplit[(size_t)(k * 256 + tid) * 8];
#pragma unroll
    for (int k = 0; k < 4; ++k)
        *(uint4*)&Bt[(size_t)(k * 256 + tid) * 8] = pr[k];
    __syncthreads();

    for (int jt = 0; jt < 32; ++jt) {
        const int j0 = jt * 128;

        // per-col C-bias for the 8 col-tiles (col = j0 + t*16 + l16)
        float hp[8];
#pragma unroll
        for (int t = 0; t < 8; ++t) {
            int jc = j0 + t * 16 + l16;
            float g = use_prev ? hvec[jc] : 0.f;
            hp[t] = epsblog + g - colnorm[jc];
        }

        // prefetch next tile into registers (consumed after the barrier)
        {
            const ushort* gsrc = colsplit + (size_t)((jt + 1) & 31) * 2048 * 8;
#pragma unroll
            for (int k = 0; k < 4; ++k)
                pr[k] = *(const uint4*)&gsrc[(size_t)(k * 256 + tid) * 8];
        }

        f32x4 acc[8];
#pragma unroll
        for (int t = 0; t < 8; ++t)
#pragma unroll
            for (int r = 0; r < 4; ++r) acc[t][r] = hp[t];

        // MFMA: per kc, per t-quad: 4 independent ah-MFMAs then 4 al-MFMAs
#pragma unroll
        for (int kc = 0; kc < 2; ++kc) {
            const int gofs = (kc * 4 + q) * 128 * 8;   // ushort offset of chunk row
#pragma unroll
            for (int tg = 0; tg < 2; ++tg) {
                s16x8 bf[4];
#pragma unroll
                for (int u = 0; u < 4; ++u) {
                    int t = tg * 4 + u;
                    bf[u] = *(const s16x8*)&Bt[gofs + (t * 16 + l16) * 8];
                }
#pragma unroll
                for (int u = 0; u < 4; ++u)
                    acc[tg * 4 + u] = __builtin_amdgcn_mfma_f32_16x16x32_bf16(
                        ah[kc], bf[u], acc[tg * 4 + u], 0, 0, 0);
#pragma unroll
                for (int u = 0; u < 4; ++u)
                    acc[tg * 4 + u] = __builtin_amdgcn_mfma_f32_16x16x32_bf16(
                        al[kc], bf[u], acc[tg * 4 + u], 0, 0, 0);
            }
        }

        // flash update: 8 values per output-row register r
#pragma unroll
        for (int r = 0; r < 4; ++r) {
            float v0 = acc[0][r], v1 = acc[1][r], v2 = acc[2][r], v3 = acc[3][r];
            float v4 = acc[4][r], v5 = acc[5][r], v6 = acc[6][r], v7 = acc[7][r];
            float t0 = fmaxf(fmaxf(v0, v1), fmaxf(v2, v3));
            float t1 = fmaxf(fmaxf(v4, v5), fmaxf(v6, v7));
            float mn = fmaxf(fmaxf(t0, t1), m[r]);
            float tt = -se * mn;
            float e0 = exp2f(fmaf(v0, se, tt));
            float e1 = exp2f(fmaf(v1, se, tt));
            float e2 = exp2f(fmaf(v2, se, tt));
            float e3 = exp2f(fmaf(v3, se, tt));
            float e4 = exp2f(fmaf(v4, se, tt));
            float e5 = exp2f(fmaf(v5, se, tt));
            float e6 = exp2f(fmaf(v6, se, tt));
            float e7 = exp2f(fmaf(v7, se, tt));
            float rs = exp2f(fmaf(m[r], se, tt));
            float sum = ((e0 + e1) + (e2 + e3)) + ((e4 + e5) + (e6 + e7));
            l[r] = fmaf(l[r], rs, sum);
            m[r] = mn;
        }

        __syncthreads();   // readers done with Bt (pr loads long in flight)
#pragma unroll
        for (int k = 0; k < 4; ++k)
            *(uint4*)&Bt[(size_t)(k * 256 + tid) * 8] = pr[k];
        __syncthreads();   // Bt = next tile
    }

    // merge the 16 col-lanes (lane bits 0..3) sharing each row
#pragma unroll
    for (int off = 1; off < 16; off <<= 1) {
#pragma unroll
        for (int r = 0; r < 4; ++r) {
            float mo = __shfl_xor(m[r], off);
            float lo = __shfl_xor(l[r], off);
            float mn = fmaxf(m[r], mo);
            float tt = -se * mn;
            l[r] = fmaf(l[r], exp2f(fmaf(m[r], se, tt)),
                        lo * exp2f(fmaf(mo, se, tt)));
            m[r] = mn;
        }
    }

    if (l16 == 0) {
        const float epsln2 = eps * LN2_F;
#pragma unroll
        for (int r = 0; r < 4; ++r) {
            int i = i0 + wave * 16 + q * 4 + r;   // C/D: row=(lane>>4)*4+reg (m89/m91)
            float f = rownorm[i] - m[r] - epsln2 * log2f(l[r]);
            if (do_avg) f = 0.5f * (avgvec[i] + f);
            outvec[i] = f;
        }
    }
}

// loss = [ sum_{b,i} (f_ba - f_aa) + (g_ab - g_bb) ] / (N*B)
__global__ __launch_bounds__(256) void reduce_kernel(const float* __restrict__ fin,
                                                     float* __restrict__ out) {
    float s = 0.f;
    for (int idx = threadIdx.x; idx < 4 * 4 * NPTS; idx += 256) {
        int mat = idx >> 14;
        float v = fin[idx];
        s += (mat < 2) ? v : -v;
    }
#pragma unroll
    for (int off = 32; off > 0; off >>= 1) s += __shfl_down(s, off);
    __shared__ float red[4];
    if ((threadIdx.x & 63) == 0) red[threadIdx.x >> 6] = s;
    __syncthreads();
    if (threadIdx.x == 0) {
        float t = red[0] + red[1] + red[2] + red[3];
        out[0] = t * (1.0f / (4096.0f * 4.0f));
    }
}

extern "C" void kernel_launch(void* const* d_in, const int* in_sizes, int n_in,
                              void* d_out, int out_size, void* d_ws, size_t ws_size,
                              hipStream_t stream) {
    const float* x = (const float*)d_in[0];
    const float* y = (const float*)d_in[1];
    float* out = (float*)d_out;

    float* norms = (float*)d_ws;             // 32768 floats
    float* bufA  = norms + 32768;            // 65536 floats: [mat][b][i]
    float* bufB  = bufA + 65536;             // 65536 floats
    ushort* split = (ushort*)(bufB + 65536); // 8 MB staging-order hi/lo

    // eps schedule: exp(arange(2*ln16, 2*ln0.05, 2*ln0.9)) ++ [0.05^2]
    const double start = 2.0 * log(16.0);
    const double stop  = 2.0 * log(0.05);
    const double step  = 2.0 * log(0.9);
    float eps_list[64];
    int ne = 0;
    for (int k = 0;; ++k) {
        double e = start + k * step;
        if (!(e > stop)) break;
        eps_list[ne++] = (float)exp(e);
    }
    eps_list[ne++] = (float)(0.05 * 0.05);   // 56 entries

    norms_kernel<<<128, 256, 0, stream>>>(x, y, norms);
    split_kernel<<<1024, 256, 0, stream>>>(x, y, split);

    // init at eps0 (no prev potentials, no averaging)
    softmin_kernel<<<1024, 256, 0, stream>>>(split, norms, bufB, bufA,
                                             eps_list[0], 0, 0);
    float* prev = bufA;
    float* next = bufB;
    for (int t = 0; t < ne; ++t) {
        softmin_kernel<<<1024, 256, 0, stream>>>(split, norms, prev, next,
                                                 eps_list[t], 1, 1);
        float* tmp = prev; prev = next; next = tmp;
    }
    // final extrapolation at eps = blur^p, no averaging
    softmin_kernel<<<1024, 256, 0, stream>>>(split, norms, prev, next,
                                             eps_list[ne - 1], 1, 0);

    reduce_kernel<<<1, 256, 0, stream>>>(next, out);
}

// Round 5
// 7800.923 us; speedup vs baseline: 1.2809x; 1.2809x over previous
//
#include <hip/hip_runtime.h>
#include <cmath>

#define NPTS 4096
#define LOG2E_F 1.4426950408889634f
#define LN2_F   0.6931471805599453f
#define BLOG_F  -8.31776616671934f   /* -ln(4096) */

typedef __attribute__((ext_vector_type(8))) short s16x8;
typedef __attribute__((ext_vector_type(4))) float f32x4;

__device__ __forceinline__ ushort bf16h(float f) {
    uint u = __float_as_uint(f);
    return (ushort)((u + 0x7fffu + ((u >> 16) & 1u)) >> 16);
}
__device__ __forceinline__ float bf16tof(ushort h) {
    return __uint_as_float(((uint)h) << 16);
}

// norms[0][b][i] = 0.5*|x_i|^2 ; norms[1][b][i] = 0.5*|y_i|^2
__global__ __launch_bounds__(256) void norms_kernel(const float* __restrict__ x,
                                                    const float* __restrict__ y,
                                                    float* __restrict__ norms) {
    int flat = blockIdx.x * 256 + threadIdx.x;   // 0..32767
    int which = flat >> 14;
    int rem = flat & 16383;
    int b = rem >> 12;
    int i = rem & 4095;
    const float* p = (which ? y : x) + (size_t)b * 64 * NPTS + i;
    float s = 0.f;
#pragma unroll
    for (int c = 0; c < 64; ++c) {
        float v = p[(size_t)c * NPTS];
        s += v * v;
    }
    norms[flat] = 0.5f * s;
}

// Split prepass, fragment-order layout:
//   split[(which*4+b)][tile128 = n>>7][chunk = g*128 + (n&127)][8 ushorts]
//   g 0..7 = hi comp-octets (comps g*8..g*8+7), g 8..15 = lo octets.
__global__ __launch_bounds__(256) void split_kernel(const float* __restrict__ x,
                                                    const float* __restrict__ y,
                                                    ushort* __restrict__ split) {
    int flat = blockIdx.x * 256 + threadIdx.x;   // 0..262143
    int n = flat & 4095;
    int g = (flat >> 12) & 7;
    int b = (flat >> 15) & 3;
    int which = flat >> 17;
    const float* src = (which ? y : x) + (size_t)b * 64 * NPTS + (size_t)g * 8 * NPTS + n;
    size_t base = ((size_t)(which * 4 + b) * 32 + (n >> 7)) * 2048 + (n & 127);
    ushort hh[8], ll[8];
#pragma unroll
    for (int e = 0; e < 8; ++e) {
        float v = src[(size_t)e * NPTS];
        hh[e] = bf16h(v);
        ll[e] = bf16h(v - bf16tof(hh[e]));
    }
    uint4 hw, lw;
    hw.x = (uint)hh[0] | ((uint)hh[1] << 16);
    hw.y = (uint)hh[2] | ((uint)hh[3] << 16);
    hw.z = (uint)hh[4] | ((uint)hh[5] << 16);
    hw.w = (uint)hh[6] | ((uint)hh[7] << 16);
    lw.x = (uint)ll[0] | ((uint)ll[1] << 16);
    lw.y = (uint)ll[2] | ((uint)ll[3] << 16);
    lw.z = (uint)ll[4] | ((uint)ll[5] << 16);
    lw.w = (uint)ll[6] | ((uint)ll[7] << 16);
    *(uint4*)&split[(base + (size_t)g * 128) * 8]       = hw;
    *(uint4*)&split[(base + (size_t)(g + 8) * 128) * 8] = lw;
}

// One annealing phase. 16x16x32 bf16 MFMA, 2-pass split (ah*bh + al*bh).
// No LDS, no barriers: B fragments read straight from L2-resident split data.
// acc init = eps*blog + (prevaux[j] or -yn_j); s_nat = acc/eps.
// aux[i] = f[i] - norm[i] written by the epilogue for the next phase.
__global__ __launch_bounds__(256, 4) void softmin_kernel(
    const ushort* __restrict__ split, const float* __restrict__ norms,
    const float* __restrict__ prev, const float* __restrict__ prevaux,
    float* __restrict__ next, float* __restrict__ nextaux,
    float eps, int use_prev, int do_avg)
{
    const int tid   = threadIdx.x;
    const int bid   = blockIdx.x;
    const int b     = bid & 3;           // round-robin XCDs -> one batch per XCD
    const int mat   = (bid >> 2) & 3;
    const int itile = bid >> 4;          // 0..63 (64-row tiles)

    const int row_is_x = (mat == 0 || mat == 2);
    const int col_is_x = (mat == 1 || mat == 2);
    const ushort* rowsplit = split + (size_t)((row_is_x ? 0 : 4) + b) * 32 * 2048 * 8;
    const ushort* colsplit = split + (size_t)((col_is_x ? 0 : 4) + b) * 32 * 2048 * 8;
    const float* rownorm = norms + (row_is_x ? 0 : 16384) + b * NPTS;
    const float* colnorm = norms + (col_is_x ? 0 : 16384) + b * NPTS;
    const int hmat = (mat == 0) ? 1 : ((mat == 1) ? 0 : mat);
    const float* hauxv  = prevaux + (size_t)(hmat * 4 + b) * NPTS;
    const float* avgvec = prev + (size_t)(mat  * 4 + b) * NPTS;
    float*       outvec = next + (size_t)(mat  * 4 + b) * NPTS;
    float*       auxvec = nextaux + (size_t)(mat * 4 + b) * NPTS;

    const float se      = (1.0f / eps) * LOG2E_F;
    const float epsblog = eps * BLOG_F;

    const int wave = tid >> 6;
    const int lane = tid & 63;
    const int l16  = lane & 15;    // A row / B col / D col
    const int q    = lane >> 4;    // k-quad for A/B, row-quad for D
    const int i0   = itile * 64;
    const int arow = i0 + wave * 16 + l16;

    // ---- A fragments (hi + lo), once per block, from pre-split global
    s16x8 ah[2], al[2];
    {
        const ushort* abase = rowsplit + ((size_t)(arow >> 7) * 2048 + (arow & 127)) * 8;
#pragma unroll
        for (int kc = 0; kc < 2; ++kc) {
            int g = kc * 4 + q;
            ah[kc] = *(const s16x8*)&abase[(size_t)g * 128 * 8];
            al[kc] = *(const s16x8*)&abase[(size_t)(g + 8) * 128 * 8];
        }
    }

    float m[4], l[4];
#pragma unroll
    for (int r = 0; r < 4; ++r) { m[r] = -__builtin_inff(); l[r] = 0.f; }

    for (int jt = 0; jt < 32; ++jt) {
        const int j0 = jt * 128;

        // acc init = per-col C-bias (col = j0 + t*16 + l16)
        f32x4 acc[8];
#pragma unroll
        for (int t = 0; t < 8; ++t) {
            int jc = j0 + t * 16 + l16;
            float h = use_prev ? (epsblog + hauxv[jc])
                               : (epsblog - colnorm[jc]);
#pragma unroll
            for (int r = 0; r < 4; ++r) acc[t][r] = h;
        }

        // B-hi fragments from global (L2-resident), 2 K-chunks of 32
#pragma unroll
        for (int kc = 0; kc < 2; ++kc) {
            const ushort* gk = colsplit +
                ((size_t)jt * 2048 + (size_t)(kc * 4 + q) * 128) * 8;
            s16x8 bf[8];
#pragma unroll
            for (int t = 0; t < 8; ++t)
                bf[t] = *(const s16x8*)&gk[(size_t)(t * 16 + l16) * 8];
#pragma unroll
            for (int t = 0; t < 8; ++t)
                acc[t] = __builtin_amdgcn_mfma_f32_16x16x32_bf16(
                    ah[kc], bf[t], acc[t], 0, 0, 0);
#pragma unroll
            for (int t = 0; t < 8; ++t)
                acc[t] = __builtin_amdgcn_mfma_f32_16x16x32_bf16(
                    al[kc], bf[t], acc[t], 0, 0, 0);
        }

        // flash update: 8 cols per output-row register r
#pragma unroll
        for (int r = 0; r < 4; ++r) {
            float v0 = acc[0][r], v1 = acc[1][r], v2 = acc[2][r], v3 = acc[3][r];
            float v4 = acc[4][r], v5 = acc[5][r], v6 = acc[6][r], v7 = acc[7][r];
            float t0 = fmaxf(fmaxf(v0, v1), fmaxf(v2, v3));
            float t1 = fmaxf(fmaxf(v4, v5), fmaxf(v6, v7));
            float mn = fmaxf(fmaxf(t0, t1), m[r]);
            float tt = -se * mn;
            float e0 = exp2f(fmaf(v0, se, tt));
            float e1 = exp2f(fmaf(v1, se, tt));
            float e2 = exp2f(fmaf(v2, se, tt));
            float e3 = exp2f(fmaf(v3, se, tt));
            float e4 = exp2f(fmaf(v4, se, tt));
            float e5 = exp2f(fmaf(v5, se, tt));
            float e6 = exp2f(fmaf(v6, se, tt));
            float e7 = exp2f(fmaf(v7, se, tt));
            float rs = exp2f(fmaf(m[r], se, tt));
            float sum = ((e0 + e1) + (e2 + e3)) + ((e4 + e5) + (e6 + e7));
            l[r] = fmaf(l[r], rs, sum);
            m[r] = mn;
        }
    }

    // merge the 16 col-lanes (lane bits 0..3) sharing each row
#pragma unroll
    for (int off = 1; off < 16; off <<= 1) {
#pragma unroll
        for (int r = 0; r < 4; ++r) {
            float mo = __shfl_xor(m[r], off);
            float lo = __shfl_xor(l[r], off);
            float mn = fmaxf(m[r], mo);
            float tt = -se * mn;
            l[r] = fmaf(l[r], exp2f(fmaf(m[r], se, tt)),
                        lo * exp2f(fmaf(mo, se, tt)));
            m[r] = mn;
        }
    }

    if (l16 == 0) {
        const float epsln2 = eps * LN2_F;
#pragma unroll
        for (int r = 0; r < 4; ++r) {
            int i = i0 + wave * 16 + q * 4 + r;   // C/D: row=(lane>>4)*4+reg (m89/m91)
            float nrm = rownorm[i];
            float f = nrm - m[r] - epsln2 * log2f(l[r]);
            if (do_avg) f = 0.5f * (avgvec[i] + f);
            outvec[i] = f;
            auxvec[i] = f - nrm;    // pre-folded bias for the next phase
        }
    }
}

// loss = [ sum_{b,i} (f_ba - f_aa) + (g_ab - g_bb) ] / (N*B)
__global__ __launch_bounds__(256) void reduce_kernel(const float* __restrict__ fin,
                                                     float* __restrict__ out) {
    float s = 0.f;
    for (int idx = threadIdx.x; idx < 4 * 4 * NPTS; idx += 256) {
        int mat = idx >> 14;
        float v = fin[idx];
        s += (mat < 2) ? v : -v;
    }
#pragma unroll
    for (int off = 32; off > 0; off >>= 1) s += __shfl_down(s, off);
    __shared__ float red[4];
    if ((threadIdx.x & 63) == 0) red[threadIdx.x >> 6] = s;
    __syncthreads();
    if (threadIdx.x == 0) {
        float t = red[0] + red[1] + red[2] + red[3];
        out[0] = t * (1.0f / (4096.0f * 4.0f));
    }
}

extern "C" void kernel_launch(void* const* d_in, const int* in_sizes, int n_in,
                              void* d_out, int out_size, void* d_ws, size_t ws_size,
                              hipStream_t stream) {
    const float* x = (const float*)d_in[0];
    const float* y = (const float*)d_in[1];
    float* out = (float*)d_out;

    float* norms = (float*)d_ws;             // 32768 floats
    float* bufA  = norms + 32768;            // 65536 floats: [mat][b][i]
    float* bufB  = bufA + 65536;
    float* auxA  = bufB + 65536;             // 65536 floats: f - norm
    float* auxB  = auxA + 65536;
    ushort* split = (ushort*)(auxB + 65536); // 8 MB fragment-order hi/lo

    // eps schedule: exp(arange(2*ln16, 2*ln0.05, 2*ln0.9)) ++ [0.05^2]
    const double start = 2.0 * log(16.0);
    const double stop  = 2.0 * log(0.05);
    const double step  = 2.0 * log(0.9);
    float eps_list[64];
    int ne = 0;
    for (int k = 0;; ++k) {
        double e = start + k * step;
        if (!(e > stop)) break;
        eps_list[ne++] = (float)exp(e);
    }
    eps_list[ne++] = (float)(0.05 * 0.05);   // 56 entries

    norms_kernel<<<128, 256, 0, stream>>>(x, y, norms);
    split_kernel<<<1024, 256, 0, stream>>>(x, y, split);

    // init at eps0 (no prev potentials, no averaging)
    softmin_kernel<<<1024, 256, 0, stream>>>(split, norms, bufB, auxB,
                                             bufA, auxA, eps_list[0], 0, 0);
    float* prev = bufA;  float* prevaux = auxA;
    float* next = bufB;  float* nextaux = auxB;
    for (int t = 0; t < ne; ++t) {
        softmin_kernel<<<1024, 256, 0, stream>>>(split, norms, prev, prevaux,
                                                 next, nextaux, eps_list[t], 1, 1);
        float* tf = prev; prev = next; next = tf;
        float* ta = prevaux; prevaux = nextaux; nextaux = ta;
    }
    // final extrapolation at eps = blur^p, no averaging
    softmin_kernel<<<1024, 256, 0, stream>>>(split, norms, prev, prevaux,
                                             next, nextaux, eps_list[ne - 1], 1, 0);

    reduce_kernel<<<1, 256, 0, stream>>>(next, out);
}

// Round 6
// 7114.127 us; speedup vs baseline: 1.4046x; 1.0965x over previous
//
#include <hip/hip_runtime.h>
#include <cmath>

#define NPTS 4096
#define LOG2E_F 1.4426950408889634f
#define LN2_F   0.6931471805599453f
#define BLOG_F  -8.31776616671934f   /* -ln(4096) */

#if __has_builtin(__builtin_amdgcn_exp2f)
#define EXP2F(x) __builtin_amdgcn_exp2f(x)
#else
#define EXP2F(x) exp2f(x)
#endif
#if __has_builtin(__builtin_amdgcn_logf)
#define LOG2F(x) __builtin_amdgcn_logf(x)
#else
#define LOG2F(x) log2f(x)
#endif

typedef __attribute__((ext_vector_type(8))) short s16x8;
typedef __attribute__((ext_vector_type(4))) float f32x4;

__device__ __forceinline__ ushort bf16h(float f) {
    uint u = __float_as_uint(f);
    return (ushort)((u + 0x7fffu + ((u >> 16) & 1u)) >> 16);
}
__device__ __forceinline__ float bf16tof(ushort h) {
    return __uint_as_float(((uint)h) << 16);
}

// norms[0][b][i] = 0.5*|x_i|^2 ; norms[1][b][i] = 0.5*|y_i|^2
__global__ __launch_bounds__(256) void norms_kernel(const float* __restrict__ x,
                                                    const float* __restrict__ y,
                                                    float* __restrict__ norms) {
    int flat = blockIdx.x * 256 + threadIdx.x;   // 0..32767
    int which = flat >> 14;
    int rem = flat & 16383;
    int b = rem >> 12;
    int i = rem & 4095;
    const float* p = (which ? y : x) + (size_t)b * 64 * NPTS + i;
    float s = 0.f;
#pragma unroll
    for (int c = 0; c < 64; ++c) {
        float v = p[(size_t)c * NPTS];
        s += v * v;
    }
    norms[flat] = 0.5f * s;
}

// Split prepass, fragment-order layout:
//   split[(which*4+b)][tile128 = n>>7][chunk = g*128 + (n&127)][8 ushorts]
//   g 0..7 = hi comp-octets (comps g*8..g*8+7), g 8..15 = lo octets.
__global__ __launch_bounds__(256) void split_kernel(const float* __restrict__ x,
                                                    const float* __restrict__ y,
                                                    ushort* __restrict__ split) {
    int flat = blockIdx.x * 256 + threadIdx.x;   // 0..262143
    int n = flat & 4095;
    int g = (flat >> 12) & 7;
    int b = (flat >> 15) & 3;
    int which = flat >> 17;
    const float* src = (which ? y : x) + (size_t)b * 64 * NPTS + (size_t)g * 8 * NPTS + n;
    size_t base = ((size_t)(which * 4 + b) * 32 + (n >> 7)) * 2048 + (n & 127);
    ushort hh[8], ll[8];
#pragma unroll
    for (int e = 0; e < 8; ++e) {
        float v = src[(size_t)e * NPTS];
        hh[e] = bf16h(v);
        ll[e] = bf16h(v - bf16tof(hh[e]));
    }
    uint4 hw, lw;
    hw.x = (uint)hh[0] | ((uint)hh[1] << 16);
    hw.y = (uint)hh[2] | ((uint)hh[3] << 16);
    hw.z = (uint)hh[4] | ((uint)hh[5] << 16);
    hw.w = (uint)hh[6] | ((uint)hh[7] << 16);
    lw.x = (uint)ll[0] | ((uint)ll[1] << 16);
    lw.y = (uint)ll[2] | ((uint)ll[3] << 16);
    lw.z = (uint)ll[4] | ((uint)ll[5] << 16);
    lw.w = (uint)ll[6] | ((uint)ll[7] << 16);
    *(uint4*)&split[(base + (size_t)g * 128) * 8]       = hw;
    *(uint4*)&split[(base + (size_t)(g + 8) * 128) * 8] = lw;
}

// One annealing phase. 16x16x32 bf16 MFMA, 2-pass split (ah*bh + al*bh).
// No LDS staging; B fragments straight from L2-resident split data.
// j-split: wave pair (w>>1) covers half the jt range; cross-wave merge in LDS.
// acc init = eps*blog + (prevaux[j] or -yn_j); s_nat = acc; exp args scaled se.
__global__ __launch_bounds__(256, 6) void softmin_kernel(
    const ushort* __restrict__ split, const float* __restrict__ norms,
    const float* __restrict__ prev, const float* __restrict__ prevaux,
    float* __restrict__ next, float* __restrict__ nextaux,
    float eps, int use_prev, int do_avg)
{
    __shared__ float2 mergebuf[4][16];

    const int tid   = threadIdx.x;
    const int bid   = blockIdx.x;
    const int b     = bid & 3;           // round-robin XCDs -> one batch per XCD
    const int mat   = (bid >> 2) & 3;
    const int itile = bid >> 4;          // 0..127 (32-row tiles)

    const int row_is_x = (mat == 0 || mat == 2);
    const int col_is_x = (mat == 1 || mat == 2);
    const ushort* rowsplit = split + (size_t)((row_is_x ? 0 : 4) + b) * 32 * 2048 * 8;
    const ushort* colsplit = split + (size_t)((col_is_x ? 0 : 4) + b) * 32 * 2048 * 8;
    const float* rownorm = norms + (row_is_x ? 0 : 16384) + b * NPTS;
    const float* colnorm = norms + (col_is_x ? 0 : 16384) + b * NPTS;
    const int hmat = (mat == 0) ? 1 : ((mat == 1) ? 0 : mat);
    const float* hauxv  = prevaux + (size_t)(hmat * 4 + b) * NPTS;
    const float* avgvec = prev + (size_t)(mat  * 4 + b) * NPTS;
    float*       outvec = next + (size_t)(mat  * 4 + b) * NPTS;
    float*       auxvec = nextaux + (size_t)(mat * 4 + b) * NPTS;

    const float se      = (1.0f / eps) * LOG2E_F;
    const float epsblog = eps * BLOG_F;

    const int wave  = tid >> 6;
    const int lane  = tid & 63;
    const int l16   = lane & 15;    // A row / B col
    const int q     = lane >> 4;    // k-quad for A/B, row-quad for D
    const int rhalf = wave & 1;     // which 16-row strip
    const int jhalf = wave >> 1;    // which jt half
    const int i0    = itile * 32;
    const int arow  = i0 + rhalf * 16 + l16;

    // ---- A fragments (hi + lo), once per block, from pre-split global
    s16x8 ah[2], al[2];
    {
        const ushort* abase = rowsplit + ((size_t)(arow >> 7) * 2048 + (arow & 127)) * 8;
#pragma unroll
        for (int kc = 0; kc < 2; ++kc) {
            int g = kc * 4 + q;
            ah[kc] = *(const s16x8*)&abase[(size_t)g * 128 * 8];
            al[kc] = *(const s16x8*)&abase[(size_t)(g + 8) * 128 * 8];
        }
    }

    float m[4], l[4];
#pragma unroll
    for (int r = 0; r < 4; ++r) { m[r] = -__builtin_inff(); l[r] = 0.f; }

    const int jt0 = jhalf * 16;
    for (int jt = jt0; jt < jt0 + 16; ++jt) {
        const int j0 = jt * 128;

        // acc init = per-col C-bias (col = j0 + t*16 + l16)
        f32x4 acc[8];
#pragma unroll
        for (int t = 0; t < 8; ++t) {
            int jc = j0 + t * 16 + l16;
            float h = use_prev ? (epsblog + hauxv[jc])
                               : (epsblog - colnorm[jc]);
#pragma unroll
            for (int r = 0; r < 4; ++r) acc[t][r] = h;
        }

        // B-hi fragments from global (L1/L2-resident), 2 K-chunks of 32
#pragma unroll
        for (int kc = 0; kc < 2; ++kc) {
            const ushort* gk = colsplit +
                ((size_t)jt * 2048 + (size_t)(kc * 4 + q) * 128) * 8;
            s16x8 bf[8];
#pragma unroll
            for (int t = 0; t < 8; ++t)
                bf[t] = *(const s16x8*)&gk[(size_t)(t * 16 + l16) * 8];
#pragma unroll
            for (int t = 0; t < 8; ++t)
                acc[t] = __builtin_amdgcn_mfma_f32_16x16x32_bf16(
                    ah[kc], bf[t], acc[t], 0, 0, 0);
#pragma unroll
            for (int t = 0; t < 8; ++t)
                acc[t] = __builtin_amdgcn_mfma_f32_16x16x32_bf16(
                    al[kc], bf[t], acc[t], 0, 0, 0);
        }

        // flash update: 8 cols per output-row register r
#pragma unroll
        for (int r = 0; r < 4; ++r) {
            float v0 = acc[0][r], v1 = acc[1][r], v2 = acc[2][r], v3 = acc[3][r];
            float v4 = acc[4][r], v5 = acc[5][r], v6 = acc[6][r], v7 = acc[7][r];
            float t0 = fmaxf(fmaxf(v0, v1), fmaxf(v2, v3));
            float t1 = fmaxf(fmaxf(v4, v5), fmaxf(v6, v7));
            float mn = fmaxf(fmaxf(t0, t1), m[r]);
            float tt = -se * mn;
            float e0 = EXP2F(fmaf(v0, se, tt));
            float e1 = EXP2F(fmaf(v1, se, tt));
            float e2 = EXP2F(fmaf(v2, se, tt));
            float e3 = EXP2F(fmaf(v3, se, tt));
            float e4 = EXP2F(fmaf(v4, se, tt));
            float e5 = EXP2F(fmaf(v5, se, tt));
            float e6 = EXP2F(fmaf(v6, se, tt));
            float e7 = EXP2F(fmaf(v7, se, tt));
            float rs = EXP2F(fmaf(m[r], se, tt));
            float sum = ((e0 + e1) + (e2 + e3)) + ((e4 + e5) + (e6 + e7));
            l[r] = fmaf(l[r], rs, sum);
            m[r] = mn;
        }
    }

    // merge the 16 col-lanes (lane bits 0..3) sharing each row
#pragma unroll
    for (int off = 1; off < 16; off <<= 1) {
#pragma unroll
        for (int r = 0; r < 4; ++r) {
            float mo = __shfl_xor(m[r], off);
            float lo = __shfl_xor(l[r], off);
            float mn = fmaxf(m[r], mo);
            float tt = -se * mn;
            l[r] = fmaf(l[r], EXP2F(fmaf(m[r], se, tt)),
                        lo * EXP2F(fmaf(mo, se, tt)));
            m[r] = mn;
        }
    }

    // cross-wave merge: waves (w, w^2) hold the two jt-halves of the same rows
    if (l16 == 0) {
#pragma unroll
        for (int r = 0; r < 4; ++r)
            mergebuf[wave][q * 4 + r] = make_float2(m[r], l[r]);
    }
    __syncthreads();

    if (wave < 2 && lane < 16) {
        float2 pa = mergebuf[wave][l16];       // row-strip `wave`, jt half 0
        float2 pb = mergebuf[wave + 2][l16];   // same rows, jt half 1
        float mn = fmaxf(pa.x, pb.x);
        float tt = -se * mn;
        float lc = pa.y * EXP2F(fmaf(pa.x, se, tt))
                 + pb.y * EXP2F(fmaf(pb.x, se, tt));
        int i = i0 + wave * 16 + l16;          // C/D row=(lane>>4)*4+reg folded via merge
        float nrm = rownorm[i];
        float f = nrm - mn - eps * LN2_F * LOG2F(lc);
        if (do_avg) f = 0.5f * (avgvec[i] + f);
        outvec[i] = f;
        auxvec[i] = f - nrm;    // pre-folded bias for the next phase
    }
}

// loss = [ sum_{b,i} (f_ba - f_aa) + (g_ab - g_bb) ] / (N*B)
__global__ __launch_bounds__(256) void reduce_kernel(const float* __restrict__ fin,
                                                     float* __restrict__ out) {
    float s = 0.f;
    for (int idx = threadIdx.x; idx < 4 * 4 * NPTS; idx += 256) {
        int mat = idx >> 14;
        float v = fin[idx];
        s += (mat < 2) ? v : -v;
    }
#pragma unroll
    for (int off = 32; off > 0; off >>= 1) s += __shfl_down(s, off);
    __shared__ float red[4];
    if ((threadIdx.x & 63) == 0) red[threadIdx.x >> 6] = s;
    __syncthreads();
    if (threadIdx.x == 0) {
        float t = red[0] + red[1] + red[2] + red[3];
        out[0] = t * (1.0f / (4096.0f * 4.0f));
    }
}

extern "C" void kernel_launch(void* const* d_in, const int* in_sizes, int n_in,
                              void* d_out, int out_size, void* d_ws, size_t ws_size,
                              hipStream_t stream) {
    const float* x = (const float*)d_in[0];
    const float* y = (const float*)d_in[1];
    float* out = (float*)d_out;

    float* norms = (float*)d_ws;             // 32768 floats
    float* bufA  = norms + 32768;            // 65536 floats: [mat][b][i]
    float* bufB  = bufA + 65536;
    float* auxA  = bufB + 65536;             // 65536 floats: f - norm
    float* auxB  = auxA + 65536;
    ushort* split = (ushort*)(auxB + 65536); // 8 MB fragment-order hi/lo

    // eps schedule: exp(arange(2*ln16, 2*ln0.05, 2*ln0.9)) ++ [0.05^2]
    const double start = 2.0 * log(16.0);
    const double stop  = 2.0 * log(0.05);
    const double step  = 2.0 * log(0.9);
    float eps_list[64];
    int ne = 0;
    for (int k = 0;; ++k) {
        double e = start + k * step;
        if (!(e > stop)) break;
        eps_list[ne++] = (float)exp(e);
    }
    eps_list[ne++] = (float)(0.05 * 0.05);   // 56 entries

    norms_kernel<<<128, 256, 0, stream>>>(x, y, norms);
    split_kernel<<<1024, 256, 0, stream>>>(x, y, split);

    // init at eps0 (no prev potentials, no averaging)
    softmin_kernel<<<2048, 256, 0, stream>>>(split, norms, bufB, auxB,
                                             bufA, auxA, eps_list[0], 0, 0);
    float* prev = bufA;  float* prevaux = auxA;
    float* next = bufB;  float* nextaux = auxB;
    for (int t = 0; t < ne; ++t) {
        softmin_kernel<<<2048, 256, 0, stream>>>(split, norms, prev, prevaux,
                                                 next, nextaux, eps_list[t], 1, 1);
        float* tf = prev; prev = next; next = tf;
        float* ta = prevaux; prevaux = nextaux; nextaux = ta;
    }
    // final extrapolation at eps = blur^p, no averaging
    softmin_kernel<<<2048, 256, 0, stream>>>(split, norms, prev, prevaux,
                                             next, nextaux, eps_list[ne - 1], 1, 0);

    reduce_kernel<<<1, 256, 0, stream>>>(next, out);
}

// Round 7
// 4832.589 us; speedup vs baseline: 2.0677x; 1.4721x over previous
//
#include <hip/hip_runtime.h>
#include <cmath>

#define NPTS 4096
#define LOG2E_F 1.4426950408889634f
#define LN2_F   0.6931471805599453f
#define BLOG_F  -8.31776616671934f   /* -ln(4096) */

#if __has_builtin(__builtin_amdgcn_exp2f)
#define EXP2F(x) __builtin_amdgcn_exp2f(x)
#else
#define EXP2F(x) exp2f(x)
#endif
#if __has_builtin(__builtin_amdgcn_logf)
#define LOG2F(x) __builtin_amdgcn_logf(x)
#else
#define LOG2F(x) log2f(x)
#endif

typedef __attribute__((ext_vector_type(8))) short s16x8;
typedef __attribute__((ext_vector_type(4))) float f32x4;

#define GAS __attribute__((address_space(1)))
#define LAS __attribute__((address_space(3)))

__device__ __forceinline__ ushort bf16h(float f) {
    uint u = __float_as_uint(f);
    return (ushort)((u + 0x7fffu + ((u >> 16) & 1u)) >> 16);
}
__device__ __forceinline__ float bf16tof(ushort h) {
    return __uint_as_float(((uint)h) << 16);
}

// norms[0][b][i] = 0.5*|x|^2, norms[1][b][i] = 0.5*|y|^2; also initialize
// aux0[mat][b][i] = -rownorm(mat) so phase 0 runs as a regular phase (g=0).
__global__ __launch_bounds__(256) void norms_kernel(const float* __restrict__ x,
                                                    const float* __restrict__ y,
                                                    float* __restrict__ norms,
                                                    float* __restrict__ aux0) {
    int flat = blockIdx.x * 256 + threadIdx.x;   // 0..32767
    int which = flat >> 14;
    int rem = flat & 16383;
    int b = rem >> 12;
    int i = rem & 4095;
    const float* p = (which ? y : x) + (size_t)b * 64 * NPTS + i;
    float s = 0.f;
#pragma unroll
    for (int c = 0; c < 64; ++c) {
        float v = p[(size_t)c * NPTS];
        s += v * v;
    }
    s *= 0.5f;
    norms[flat] = s;
    // mats with rows == this source: which==0 -> mats 0,2 ; which==1 -> mats 1,3
    aux0[(size_t)((which ? 1 : 0) * 4 + b) * NPTS + i] = -s;
    aux0[(size_t)((which ? 3 : 2) * 4 + b) * NPTS + i] = -s;
}

// Split prepass, fragment-order layout:
//   split[(which*4+b)][tile128 = n>>7][chunk = g*128 + (n&127)][8 ushorts]
//   g 0..7 = hi comp-octets (comps g*8..g*8+7), g 8..15 = lo octets.
// Hi half of each tile block = first 16 KB (contiguous) -> DMA-friendly.
__global__ __launch_bounds__(256) void split_kernel(const float* __restrict__ x,
                                                    const float* __restrict__ y,
                                                    ushort* __restrict__ split) {
    int flat = blockIdx.x * 256 + threadIdx.x;   // 0..262143
    int n = flat & 4095;
    int g = (flat >> 12) & 7;
    int b = (flat >> 15) & 3;
    int which = flat >> 17;
    const float* src = (which ? y : x) + (size_t)b * 64 * NPTS + (size_t)g * 8 * NPTS + n;
    size_t base = ((size_t)(which * 4 + b) * 32 + (n >> 7)) * 2048 + (n & 127);
    ushort hh[8], ll[8];
#pragma unroll
    for (int e = 0; e < 8; ++e) {
        float v = src[(size_t)e * NPTS];
        hh[e] = bf16h(v);
        ll[e] = bf16h(v - bf16tof(hh[e]));
    }
    uint4 hw, lw;
    hw.x = (uint)hh[0] | ((uint)hh[1] << 16);
    hw.y = (uint)hh[2] | ((uint)hh[3] << 16);
    hw.z = (uint)hh[4] | ((uint)hh[5] << 16);
    hw.w = (uint)hh[6] | ((uint)hh[7] << 16);
    lw.x = (uint)ll[0] | ((uint)ll[1] << 16);
    lw.y = (uint)ll[2] | ((uint)ll[3] << 16);
    lw.z = (uint)ll[4] | ((uint)ll[5] << 16);
    lw.w = (uint)ll[6] | ((uint)ll[7] << 16);
    *(uint4*)&split[(base + (size_t)g * 128) * 8]       = hw;
    *(uint4*)&split[(base + (size_t)(g + 8) * 128) * 8] = lw;
}

// One annealing phase. 16x16x32 bf16 MFMA, 2-pass split (ah*bh + al*bh).
// B-tile staged in LDS via async global_load_lds, double-buffered, one
// barrier per jt. Bias (prevaux = g - colnorm) register-prefetched 1 jt ahead.
__global__ __launch_bounds__(256, 4) void softmin_kernel(
    const ushort* __restrict__ split, const float* __restrict__ norms,
    const float* __restrict__ prev, const float* __restrict__ prevaux,
    float* __restrict__ next, float* __restrict__ nextaux,
    float eps, int do_avg)
{
    __shared__ __align__(16) ushort Bt[2][8192];   // 2 x 16 KB hi-only tiles

    const int tid   = threadIdx.x;
    const int bid   = blockIdx.x;
    const int b     = bid & 3;           // XCD round-robin keeps b fixed per XCD
    const int mat   = (bid >> 2) & 3;
    const int itile = bid >> 4;          // 0..63 (64-row tiles)

    const int row_is_x = (mat == 0 || mat == 2);
    const int col_is_x = (mat == 1 || mat == 2);
    const ushort* rowsplit = split + (size_t)((row_is_x ? 0 : 4) + b) * 32 * 2048 * 8;
    const ushort* colsplit = split + (size_t)((col_is_x ? 0 : 4) + b) * 32 * 2048 * 8;
    const float* rownorm = norms + (row_is_x ? 0 : 16384) + b * NPTS;
    const int hmat = (mat == 0) ? 1 : ((mat == 1) ? 0 : mat);
    const float* hauxv  = prevaux + (size_t)(hmat * 4 + b) * NPTS;
    const float* avgvec = prev + (size_t)(mat  * 4 + b) * NPTS;
    float*       outvec = next + (size_t)(mat  * 4 + b) * NPTS;
    float*       auxvec = nextaux + (size_t)(mat * 4 + b) * NPTS;

    const float se      = (1.0f / eps) * LOG2E_F;
    const float epsblog = eps * BLOG_F;

    const int wave = tid >> 6;
    const int lane = tid & 63;
    const int l16  = lane & 15;    // A row / B col
    const int q    = lane >> 4;    // k-quad for A/B, row-quad for D
    const int i0   = itile * 64;
    const int arow = i0 + wave * 16 + l16;

    // ---- A fragments (hi + lo), once per block
    s16x8 ah[2], al[2];
    {
        const ushort* abase = rowsplit + ((size_t)(arow >> 7) * 2048 + (arow & 127)) * 8;
#pragma unroll
        for (int kc = 0; kc < 2; ++kc) {
            int g = kc * 4 + q;
            ah[kc] = *(const s16x8*)&abase[(size_t)g * 128 * 8];
            al[kc] = *(const s16x8*)&abase[(size_t)(g + 8) * 128 * 8];
        }
    }

    // ---- prologue: DMA tile 0, prefetch bias 0
    {
#pragma unroll
        for (int it = 0; it < 4; ++it) {
            int chunk = wave * 256 + it * 64 + lane;
            __builtin_amdgcn_global_load_lds(
                (const GAS uint*)(colsplit + (size_t)chunk * 8),
                (LAS uint*)(&Bt[0][chunk * 8]), 16, 0, 0);
        }
    }
    float hb[8];
#pragma unroll
    for (int t = 0; t < 8; ++t)
        hb[t] = epsblog + hauxv[t * 16 + l16];

    float m[4], l[4];
#pragma unroll
    for (int r = 0; r < 4; ++r) { m[r] = -__builtin_inff(); l[r] = 0.f; }

    __syncthreads();   // tile 0 staged

    for (int jt = 0; jt < 32; ++jt) {
        const int cur = jt & 1;

        // issue DMA for jt+1 into the other buffer; prefetch its bias
        float hbn[8];
        if (jt < 31) {
            const ushort* gsrc = colsplit + (size_t)(jt + 1) * 2048 * 8;
#pragma unroll
            for (int it = 0; it < 4; ++it) {
                int chunk = wave * 256 + it * 64 + lane;
                __builtin_amdgcn_global_load_lds(
                    (const GAS uint*)(gsrc + (size_t)chunk * 8),
                    (LAS uint*)(&Bt[cur ^ 1][chunk * 8]), 16, 0, 0);
            }
            const float* hs = hauxv + (jt + 1) * 128;
#pragma unroll
            for (int t = 0; t < 8; ++t)
                hbn[t] = epsblog + hs[t * 16 + l16];
        }

        // ---- compute on tile jt from LDS
        f32x4 acc[8];
#pragma unroll
        for (int t = 0; t < 8; ++t)
#pragma unroll
            for (int r = 0; r < 4; ++r) acc[t][r] = hb[t];

#pragma unroll
        for (int kc = 0; kc < 2; ++kc) {
            const int gofs = (kc * 4 + q) * 128 * 8;
            s16x8 bf[8];
#pragma unroll
            for (int t = 0; t < 8; ++t)
                bf[t] = *(const s16x8*)&Bt[cur][gofs + (t * 16 + l16) * 8];
#pragma unroll
            for (int t = 0; t < 8; ++t)
                acc[t] = __builtin_amdgcn_mfma_f32_16x16x32_bf16(
                    ah[kc], bf[t], acc[t], 0, 0, 0);
#pragma unroll
            for (int t = 0; t < 8; ++t)
                acc[t] = __builtin_amdgcn_mfma_f32_16x16x32_bf16(
                    al[kc], bf[t], acc[t], 0, 0, 0);
        }

        // flash update: 8 cols per output-row register r
#pragma unroll
        for (int r = 0; r < 4; ++r) {
            float v0 = acc[0][r], v1 = acc[1][r], v2 = acc[2][r], v3 = acc[3][r];
            float v4 = acc[4][r], v5 = acc[5][r], v6 = acc[6][r], v7 = acc[7][r];
            float t0 = fmaxf(fmaxf(v0, v1), fmaxf(v2, v3));
            float t1 = fmaxf(fmaxf(v4, v5), fmaxf(v6, v7));
            float mn = fmaxf(fmaxf(t0, t1), m[r]);
            float tt = -se * mn;
            float e0 = EXP2F(fmaf(v0, se, tt));
            float e1 = EXP2F(fmaf(v1, se, tt));
            float e2 = EXP2F(fmaf(v2, se, tt));
            float e3 = EXP2F(fmaf(v3, se, tt));
            float e4 = EXP2F(fmaf(v4, se, tt));
            float e5 = EXP2F(fmaf(v5, se, tt));
            float e6 = EXP2F(fmaf(v6, se, tt));
            float e7 = EXP2F(fmaf(v7, se, tt));
            float rs = EXP2F(fmaf(m[r], se, tt));
            float sum = ((e0 + e1) + (e2 + e3)) + ((e4 + e5) + (e6 + e7));
            l[r] = fmaf(l[r], rs, sum);
            m[r] = mn;
        }

#pragma unroll
        for (int t = 0; t < 8; ++t) hb[t] = hbn[t];

        __syncthreads();   // DMA for jt+1 done; all waves done reading tile jt
    }

    // merge the 16 col-lanes (lane bits 0..3) sharing each row
#pragma unroll
    for (int off = 1; off < 16; off <<= 1) {
#pragma unroll
        for (int r = 0; r < 4; ++r) {
            float mo = __shfl_xor(m[r], off);
            float lo = __shfl_xor(l[r], off);
            float mn = fmaxf(m[r], mo);
            float tt = -se * mn;
            l[r] = fmaf(l[r], EXP2F(fmaf(m[r], se, tt)),
                        lo * EXP2F(fmaf(mo, se, tt)));
            m[r] = mn;
        }
    }

    if (l16 == 0) {
        const float epsln2 = eps * LN2_F;
#pragma unroll
        for (int r = 0; r < 4; ++r) {
            int i = i0 + wave * 16 + q * 4 + r;   // C/D: row=(lane>>4)*4+reg (m89/m91)
            float nrm = rownorm[i];
            float f = nrm - m[r] - epsln2 * LOG2F(l[r]);
            if (do_avg) f = 0.5f * (avgvec[i] + f);
            outvec[i] = f;
            auxvec[i] = f - nrm;    // pre-folded bias for the next phase
        }
    }
}

// loss = [ sum_{b,i} (f_ba - f_aa) + (g_ab - g_bb) ] / (N*B)
__global__ __launch_bounds__(256) void reduce_kernel(const float* __restrict__ fin,
                                                     float* __restrict__ out) {
    float s = 0.f;
    for (int idx = threadIdx.x; idx < 4 * 4 * NPTS; idx += 256) {
        int mat = idx >> 14;
        float v = fin[idx];
        s += (mat < 2) ? v : -v;
    }
#pragma unroll
    for (int off = 32; off > 0; off >>= 1) s += __shfl_down(s, off);
    __shared__ float red[4];
    if ((threadIdx.x & 63) == 0) red[threadIdx.x >> 6] = s;
    __syncthreads();
    if (threadIdx.x == 0) {
        float t = red[0] + red[1] + red[2] + red[3];
        out[0] = t * (1.0f / (4096.0f * 4.0f));
    }
}

extern "C" void kernel_launch(void* const* d_in, const int* in_sizes, int n_in,
                              void* d_out, int out_size, void* d_ws, size_t ws_size,
                              hipStream_t stream) {
    const float* x = (const float*)d_in[0];
    const float* y = (const float*)d_in[1];
    float* out = (float*)d_out;

    float* norms = (float*)d_ws;             // 32768 floats
    float* bufA  = norms + 32768;            // 65536 floats: [mat][b][i]
    float* bufB  = bufA + 65536;
    float* auxA  = bufB + 65536;             // 65536 floats: f - rownorm
    float* auxB  = auxA + 65536;
    ushort* split = (ushort*)(auxB + 65536); // 8 MB fragment-order hi/lo

    // eps schedule: exp(arange(2*ln16, 2*ln0.05, 2*ln0.9)) ++ [0.05^2]
    const double start = 2.0 * log(16.0);
    const double stop  = 2.0 * log(0.05);
    const double step  = 2.0 * log(0.9);
    float eps_list[64];
    int ne = 0;
    for (int k = 0;; ++k) {
        double e = start + k * step;
        if (!(e > stop)) break;
        eps_list[ne++] = (float)exp(e);
    }
    eps_list[ne++] = (float)(0.05 * 0.05);   // 56 entries

    norms_kernel<<<128, 256, 0, stream>>>(x, y, norms, auxA);
    split_kernel<<<1024, 256, 0, stream>>>(x, y, split);

    // phase 0 at eps0: aux pre-initialized to -rownorm (g=0), no averaging
    softmin_kernel<<<1024, 256, 0, stream>>>(split, norms, bufB, auxA,
                                             bufA, auxB, eps_list[0], 0);
    float* prev = bufA;  float* prevaux = auxB;
    float* next = bufB;  float* nextaux = auxA;
    for (int t = 0; t < ne; ++t) {
        softmin_kernel<<<1024, 256, 0, stream>>>(split, norms, prev, prevaux,
                                                 next, nextaux, eps_list[t], 1);
        float* tf = prev; prev = next; next = tf;
        float* ta = prevaux; prevaux = nextaux; nextaux = ta;
    }
    // final extrapolation at eps = blur^p, no averaging
    softmin_kernel<<<1024, 256, 0, stream>>>(split, norms, prev, prevaux,
                                             next, nextaux, eps_list[ne - 1], 0);

    reduce_kernel<<<1, 256, 0, stream>>>(next, out);
}